// Round 10
// baseline (1922.031 us; speedup 1.0000x reference)
//
#include <hip/hip_runtime.h>

// Problem constants (B,T,D,H,FF,L,CS,LC) = (8,512,512,8,2048,6,16,4)
#define B_ 8
#define T_ 512
#define D_ 512
#define H_ 8
#define FF_ 2048
#define L_ 6
#define CS_ 16
#define LC_ 4
#define DK_ 64
#define MT_ (B_*T_)   // 4096 rows

typedef unsigned short u16;  // raw bf16
typedef __attribute__((ext_vector_type(8))) short bf8_t;   // 8 x bf16 (4 VGPR)
typedef __attribute__((ext_vector_type(4))) float f4_t;    // 4 x f32 acc

__device__ __forceinline__ float bf2f(u16 u){
  union { unsigned int i; float f; } c; c.i = ((unsigned int)u) << 16; return c.f;
}
__device__ __forceinline__ u16 f2bf(float f){
  union { float f; unsigned int i; } c; c.f = f;
  unsigned int x = c.i;
  return (u16)((x + 0x7FFFu + ((x >> 16) & 1u)) >> 16);  // RNE
}
__device__ __forceinline__ void ld_lds16(const u16* gp, u16* lp){
  __builtin_amdgcn_global_load_lds((const __attribute__((address_space(1))) void*)gp,
                                   (__attribute__((address_space(3))) void*)lp, 16, 0, 0);
}

// ---------------- init: x = xs*sqrt(D) (f32), pe_bf = bf16(pos_emb) ----------
__global__ void init_kernel(const float* __restrict__ xs, const float* __restrict__ pe,
                            float* __restrict__ x, u16* __restrict__ pe_bf)
{
  int stride = gridDim.x * blockDim.x;
  int i0 = blockIdx.x * blockDim.x + threadIdx.x;
  const float s = 22.62741699796952f;  // sqrt(512)
  for (int i = i0; i < B_*T_*D_; i += stride) x[i] = xs[i] * s;
  for (int i = i0; i < T_*D_;    i += stride) pe_bf[i] = f2bf(pe[i]);
}

// ---------------- generic transpose+convert: in f32 [K][N] -> out bf16 [N][K]
__global__ void transpose_kernel(const float* __restrict__ in, u16* __restrict__ out,
                                 int K, int N)
{
  __shared__ float tile[32][33];
  int l = blockIdx.z;
  const float* src = in + (size_t)l * K * N;
  u16* dst = out + (size_t)l * N * K;
  int n0 = blockIdx.x * 32, k0 = blockIdx.y * 32;
  int tx = threadIdx.x, ty = threadIdx.y;
  #pragma unroll
  for (int i = 0; i < 4; ++i)
    tile[ty + i*8][tx] = src[(size_t)(k0 + ty + i*8) * N + n0 + tx];
  __syncthreads();
  #pragma unroll
  for (int i = 0; i < 4; ++i)
    dst[(size_t)(n0 + ty + i*8) * K + k0 + tx] = f2bf(tile[tx][ty + i*8]);
}

// ---------------- QKV packed transpose ---------------------------------------
__global__ void transpose_qkv_kernel(const float* __restrict__ Wq, const float* __restrict__ Wk,
                                     const float* __restrict__ Wv, u16* __restrict__ out)
{
  __shared__ float tile[32][33];
  int l = blockIdx.z;
  int n0 = blockIdx.x * 32, k0 = blockIdx.y * 32;
  const float* W = (n0 < 512) ? Wq : (n0 < 1024 ? Wk : Wv);
  int nn0 = n0 & 511;
  const float* src = W + (size_t)l * D_ * D_;
  u16* dst = out + (size_t)l * 3 * D_ * D_;
  int tx = threadIdx.x, ty = threadIdx.y;
  #pragma unroll
  for (int i = 0; i < 4; ++i)
    tile[ty + i*8][tx] = src[(size_t)(k0 + ty + i*8) * D_ + nn0 + tx];
  __syncthreads();
  #pragma unroll
  for (int i = 0; i < 4; ++i)
    dst[(size_t)(n0 + ty + i*8) * D_ + k0 + tx] = f2bf(tile[tx][ty + i*8]);
}

// ---------------- bias pack: bqkv[l][1536] -----------------------------------
__global__ void pack_bias_kernel(const float* __restrict__ bq, const float* __restrict__ bk,
                                 const float* __restrict__ bv, float* __restrict__ out)
{
  int l = blockIdx.x, t = threadIdx.x;  // 512 threads
  out[l*1536 + t]        = bq[l*512 + t];
  out[l*1536 + 512  + t] = bk[l*512 + t];
  out[l*1536 + 1024 + t] = bv[l*512 + t];
}

// ---------------- LayerNorm: one wave per row, 4 rows/block ------------------
template <int OUTMODE>
__global__ __launch_bounds__(256) void ln_kernel(const float* __restrict__ x,
    const float* __restrict__ g, const float* __restrict__ b, void* __restrict__ outp)
{
  int lane = threadIdx.x & 63;
  int row  = (blockIdx.x << 2) + (threadIdx.x >> 6);
  const float* xr = x + (size_t)row * D_;
  int d = lane * 8;
  float4 a0 = *(const float4*)(xr + d);
  float4 a1 = *(const float4*)(xr + d + 4);
  float s  = a0.x+a0.y+a0.z+a0.w + a1.x+a1.y+a1.z+a1.w;
  float s2 = a0.x*a0.x+a0.y*a0.y+a0.z*a0.z+a0.w*a0.w
           + a1.x*a1.x+a1.y*a1.y+a1.z*a1.z+a1.w*a1.w;
  #pragma unroll
  for (int off = 32; off > 0; off >>= 1){ s += __shfl_xor(s, off); s2 += __shfl_xor(s2, off); }
  float m  = s * (1.0f / D_);
  float var = s2 * (1.0f / D_) - m*m;
  float rs = rsqrtf(var + 1e-5f);
  float4 g0 = *(const float4*)(g + d), g1 = *(const float4*)(g + d + 4);
  float4 b0 = *(const float4*)(b + d), b1 = *(const float4*)(b + d + 4);
  float o[8];
  o[0]=(a0.x-m)*rs*g0.x+b0.x; o[1]=(a0.y-m)*rs*g0.y+b0.y;
  o[2]=(a0.z-m)*rs*g0.z+b0.z; o[3]=(a0.w-m)*rs*g0.w+b0.w;
  o[4]=(a1.x-m)*rs*g1.x+b1.x; o[5]=(a1.y-m)*rs*g1.y+b1.y;
  o[6]=(a1.z-m)*rs*g1.z+b1.z; o[7]=(a1.w-m)*rs*g1.w+b1.w;
  if (OUTMODE == 1){
    float* outr = (float*)outp + (size_t)row * D_ + d;
    *(float4*)(outr)     = make_float4(o[0],o[1],o[2],o[3]);
    *(float4*)(outr + 4) = make_float4(o[4],o[5],o[6],o[7]);
  } else {
    u16* outr = (u16*)outp + (size_t)row * D_ + d;
    ushort4 w0, w1;
    w0.x=f2bf(o[0]); w0.y=f2bf(o[1]); w0.z=f2bf(o[2]); w0.w=f2bf(o[3]);
    w1.x=f2bf(o[4]); w1.y=f2bf(o[5]); w1.z=f2bf(o[6]); w1.w=f2bf(o[7]);
    *(ushort4*)(outr)     = w0;
    *(ushort4*)(outr + 4) = w1;
  }
}

// ---------------- MFMA GEMM: 3-deep pipeline, optional split-K+atomic --------
__global__ __launch_bounds__(256) void mgemm_kernel(
    const u16* __restrict__ A, const u16* __restrict__ Bt,
    const float* __restrict__ bias, const float* __restrict__ resid,
    void* __restrict__ C, int M, int N, int K,
    int relu, int bf16out, size_t wstride, size_t cstride, int kchunk)
{
  constexpr int TN = 64, NT = 2, S = 3;
  size_t coff = 0;
  int kbeg = 0, kend = K;
  if (kchunk > 0){
    kbeg = blockIdx.z * kchunk; kend = kbeg + kchunk;
  } else {
    Bt += (size_t)blockIdx.z * wstride;
    coff = (size_t)blockIdx.z * cstride;
  }

  __shared__ u16 As[3][128 * 32];
  __shared__ u16 Bs[3][TN * 32];

  int tid  = threadIdx.x;
  int wave = tid >> 6, lane = tid & 63;
  int wm = wave >> 1, wn = wave & 1;
  int fm = lane & 15, fq = lane >> 4;

  int m0 = blockIdx.y * 128, n0 = blockIdx.x * TN;

  f4_t acc[4][NT];
  #pragma unroll
  for (int i = 0; i < 4; ++i)
    #pragma unroll
    for (int j = 0; j < NT; ++j) acc[i][j] = (f4_t)0.0f;

  int srow = lane >> 2;
  int selem = (lane & 3) << 3;

  auto stage = [&](int bufi, int k0){
    #pragma unroll
    for (int j = 0; j < 2; ++j){
      int c = wave * 2 + j;
      ld_lds16(A + (size_t)(m0 + c*16 + srow) * K + k0 + selem, &As[bufi][c * 512]);
    }
    ld_lds16(Bt + (size_t)(n0 + wave*16 + srow) * K + k0 + selem, &Bs[bufi][wave * 512]);
  };

  stage(0, kbeg);
  if (kbeg + 32 < kend) stage(1, kbeg + 32);
  int buf = 0;
  for (int k0 = kbeg; k0 < kend; k0 += 32){
    if (k0 + 64 < kend){
      stage((buf + 2) % 3, k0 + 64);
      asm volatile("s_waitcnt vmcnt(%0)" :: "n"(2*S) : "memory");
    } else if (k0 + 32 < kend){
      asm volatile("s_waitcnt vmcnt(%0)" :: "n"(S) : "memory");
    } else {
      asm volatile("s_waitcnt vmcnt(0)" ::: "memory");
    }
    asm volatile("s_barrier" ::: "memory");

    bf8_t af[4], bfr[NT];
    #pragma unroll
    for (int mi = 0; mi < 4; ++mi)
      af[mi] = *(const bf8_t*)&As[buf][(wm*64 + mi*16 + fm) * 32 + fq*8];
    #pragma unroll
    for (int nj = 0; nj < NT; ++nj)
      bfr[nj] = *(const bf8_t*)&Bs[buf][(wn*32 + nj*16 + fm) * 32 + fq*8];
    #pragma unroll
    for (int mi = 0; mi < 4; ++mi)
      #pragma unroll
      for (int nj = 0; nj < NT; ++nj)
        acc[mi][nj] = __builtin_amdgcn_mfma_f32_16x16x32_bf16(af[mi], bfr[nj], acc[mi][nj], 0, 0, 0);

    asm volatile("s_barrier" ::: "memory");
    buf = (buf + 1) % 3;
  }

  int rbase = m0 + wm*64, cbase = n0 + wn*32;
  if (kchunk > 0){
    int addb = (blockIdx.z == 0) && bias;
    #pragma unroll
    for (int mi = 0; mi < 4; ++mi){
      #pragma unroll
      for (int nj = 0; nj < NT; ++nj){
        int col = cbase + nj*16 + fm;
        float bia = addb ? bias[col] : 0.0f;
        #pragma unroll
        for (int r = 0; r < 4; ++r){
          int row = rbase + mi*16 + fq*4 + r;
          atomicAdd((float*)C + (size_t)row * N + col, acc[mi][nj][r] + bia);
        }
      }
    }
  } else {
    #pragma unroll
    for (int mi = 0; mi < 4; ++mi){
      #pragma unroll
      for (int nj = 0; nj < NT; ++nj){
        int col = cbase + nj*16 + fm;
        float bia = bias ? bias[col] : 0.0f;
        #pragma unroll
        for (int r = 0; r < 4; ++r){
          int row = rbase + mi*16 + fq*4 + r;
          size_t idx = coff + (size_t)row * N + col;
          float val = acc[mi][nj][r] + bia;
          if (relu)  val = fmaxf(val, 0.0f);
          if (resid) val += resid[idx];
          if (bf16out) ((u16*)C)[idx] = f2bf(val);
          else         ((float*)C)[idx] = val;
        }
      }
    }
  }
}

// ---------------- Fused FF: x += relu(h@W1+b1)@W2 + b2 -----------------------
// One block per 16-row m-tile (grid 256). ff tensor never hits HBM.
#define FP_ 520   // padded row stride (bf16) for 512-col LDS tiles
__global__ __launch_bounds__(256) void ffused_kernel(
    const u16* __restrict__ h, const u16* __restrict__ w1t, const float* __restrict__ b1,
    const u16* __restrict__ w2t, const float* __restrict__ b2, float* __restrict__ x)
{
  __shared__ u16 hs[16 * FP_];
  __shared__ u16 ffs[16 * FP_];

  int tid = threadIdx.x;
  int wave = tid >> 6, lane = tid & 63;
  int fm = lane & 15, fq = lane >> 4;
  int m0 = blockIdx.x * 16;

  // load h tile: 16 rows x 512 bf16; 8 contiguous bf16 per thread-iter
  // (ushort4 = 4 bf16 -> two loads at +0 and +4). 4*256*8 = 8192 = 16*512.
  #pragma unroll
  for (int it = 0; it < 4; ++it){
    int idx = it*256 + tid;             // 0..1023
    int row = idx >> 6;                 // 0..15
    int col = (idx & 63) << 3;          // 0..504 step 8
    const u16* src = h + (size_t)(m0 + row) * D_ + col;
    *(ushort4*)(hs + row*FP_ + col)     = *(const ushort4*)(src);
    *(ushort4*)(hs + row*FP_ + col + 4) = *(const ushort4*)(src + 4);
  }
  __syncthreads();

  f4_t acc2[8];
  #pragma unroll
  for (int j = 0; j < 8; ++j) acc2[j] = (f4_t)0.0f;

  for (int nc = 0; nc < 4; ++nc){
    // ---- phase 1: wave's 128 ff cols ----
    #pragma unroll
    for (int nt = 0; nt < 8; ++nt){
      int ffc0 = nc*512 + wave*128 + nt*16;     // global ff col of this 16-tile
      f4_t c = (f4_t)0.0f;
      #pragma unroll
      for (int ks = 0; ks < 16; ++ks){
        bf8_t af = *(const bf8_t*)(hs + fm*FP_ + ks*32 + fq*8);
        bf8_t bf = *(const bf8_t*)(w1t + (size_t)(ffc0 + fm)*D_ + ks*32 + fq*8);
        c = __builtin_amdgcn_mfma_f32_16x16x32_bf16(af, bf, c, 0, 0, 0);
      }
      int col = ffc0 + fm;                       // C layout: col = lane&15
      float bia = b1[col];
      int lcol = wave*128 + nt*16 + fm;          // chunk-local col
      #pragma unroll
      for (int r = 0; r < 4; ++r){
        float v = fmaxf(c[r] + bia, 0.0f);
        ffs[(fq*4 + r)*FP_ + lcol] = f2bf(v);
      }
    }
    __syncthreads();
    // ---- phase 2: accumulate wave's 128 out cols over this K-window ----
    #pragma unroll
    for (int ks = 0; ks < 16; ++ks){
      bf8_t af = *(const bf8_t*)(ffs + fm*FP_ + ks*32 + fq*8);
      #pragma unroll
      for (int nt = 0; nt < 8; ++nt){
        int ocol = wave*128 + nt*16 + fm;
        bf8_t bf = *(const bf8_t*)(w2t + (size_t)ocol*FF_ + nc*512 + ks*32 + fq*8);
        acc2[nt] = __builtin_amdgcn_mfma_f32_16x16x32_bf16(af, bf, acc2[nt], 0, 0, 0);
      }
    }
    __syncthreads();
  }

  // ---- epilogue: x += acc2 + b2 (rows exclusive to this block) ----
  #pragma unroll
  for (int nt = 0; nt < 8; ++nt){
    int col = wave*128 + nt*16 + fm;
    float bia = b2[col];
    #pragma unroll
    for (int r = 0; r < 4; ++r){
      int row = m0 + fq*4 + r;
      float* px = x + (size_t)row * D_ + col;
      *px += acc2[nt][r] + bia;
    }
  }
}

// ---------------- Fused chunked attention (single-wave MFMA) ------------------
__global__ __launch_bounds__(64) void attn_kernel(
    const u16* __restrict__ qkv, const u16* __restrict__ p,
    const float* __restrict__ pbu, const float* __restrict__ pbv,
    u16* __restrict__ o)
{
  int ci = blockIdx.x, h = blockIdx.y, b = blockIdx.z;
  int t0 = ci * CS_;
  int cb = ci - LC_; if (cb < 0) cb = 0;
  int c0 = cb * CS_;
  int ncol = (ci + 1) * CS_ - c0;   // 16..80

  __shared__ u16 smem[15648];
  u16* qu = smem;                         // [16][64]
  u16* qv = smem + 1024;                  // [16][64]
  u16* kp = smem + 2048;                  // [80][64] K tile
  u16* pp = smem + 2048 + 5120;           // [80][64] P tile
  float* vf  = (float*)(smem + 2048);     // [80][64] f32 (aliases kp+pp)
  float* psf = (float*)(smem + 12288);    // [16][105] f32

  int lane = threadIdx.x;
  int fm = lane & 15, fq = lane >> 4;

  const u16* kbase = qkv + ((size_t)(b*T_ + c0)) * 1536 + 512 + h*DK_;
  const u16* pbase = p + (size_t)c0 * D_ + h*DK_;
  int srow8 = lane >> 3, scol = (lane & 7) << 3;
  #pragma unroll
  for (int c = 0; c < 10; ++c){
    ld_lds16(kbase + (size_t)(c*8 + srow8) * 1536 + scol, kp + c*512);
    ld_lds16(pbase + (size_t)(c*8 + srow8) * D_   + scol, pp + c*512);
  }
  const u16* qbase = qkv + ((size_t)(b*T_ + t0)) * 1536 + h*DK_;
  #pragma unroll
  for (int it = 0; it < 4; ++it){
    int i = it*256 + lane*4; int r = i >> 6; int d = i & 63;
    ushort4 w = *(const ushort4*)(qbase + (size_t)r * 1536 + d);
    float4 bu = *(const float4*)(pbu + h*DK_ + d);
    float4 bv = *(const float4*)(pbv + h*DK_ + d);
    ushort4 ou, ov;
    ou.x = f2bf(bf2f(w.x) + bu.x); ou.y = f2bf(bf2f(w.y) + bu.y);
    ou.z = f2bf(bf2f(w.z) + bu.z); ou.w = f2bf(bf2f(w.w) + bu.w);
    ov.x = f2bf(bf2f(w.x) + bv.x); ov.y = f2bf(bf2f(w.y) + bv.y);
    ov.z = f2bf(bf2f(w.z) + bv.z); ov.w = f2bf(bf2f(w.w) + bv.w);
    *(ushort4*)(qu + r*64 + d) = ou;
    *(ushort4*)(qv + r*64 + d) = ov;
  }
  __syncthreads();

  bf8_t au0 = *(const bf8_t*)(qu + fm*64 + fq*8);
  bf8_t au1 = *(const bf8_t*)(qu + fm*64 + 32 + fq*8);
  bf8_t av0 = *(const bf8_t*)(qv + fm*64 + fq*8);
  bf8_t av1 = *(const bf8_t*)(qv + fm*64 + 32 + fq*8);
  f4_t acc[5];
  #pragma unroll
  for (int nt = 0; nt < 5; ++nt) acc[nt] = (f4_t)0.0f;
  #pragma unroll
  for (int nt = 0; nt < 5; ++nt){
    const u16* kr = kp + (nt*16 + fm)*64;
    const u16* pr = pp + (nt*16 + fm)*64;
    bf8_t bk0 = *(const bf8_t*)(kr + fq*8);
    bf8_t bk1 = *(const bf8_t*)(kr + 32 + fq*8);
    bf8_t bp0 = *(const bf8_t*)(pr + fq*8);
    bf8_t bp1 = *(const bf8_t*)(pr + 32 + fq*8);
    f4_t a = acc[nt];
    a = __builtin_amdgcn_mfma_f32_16x16x32_bf16(au0, bk0, a, 0, 0, 0);
    a = __builtin_amdgcn_mfma_f32_16x16x32_bf16(au1, bk1, a, 0, 0, 0);
    a = __builtin_amdgcn_mfma_f32_16x16x32_bf16(av0, bp0, a, 0, 0, 0);
    a = __builtin_amdgcn_mfma_f32_16x16x32_bf16(av1, bp1, a, 0, 0, 0);
    acc[nt] = a;
  }

  const float scale = 0.125f;
  float mx[4], sm[4];
  float e[5][4];
  #pragma unroll
  for (int r = 0; r < 4; ++r) mx[r] = -3.0e38f;
  #pragma unroll
  for (int nt = 0; nt < 5; ++nt){
    bool valid = (nt*16 + fm) < ncol;
    #pragma unroll
    for (int r = 0; r < 4; ++r){
      float v = valid ? acc[nt][r] : -3.0e38f;
      mx[r] = fmaxf(mx[r], v);
    }
  }
  #pragma unroll
  for (int r = 0; r < 4; ++r){
    #pragma unroll
    for (int m = 1; m < 16; m <<= 1) mx[r] = fmaxf(mx[r], __shfl_xor(mx[r], m));
    sm[r] = 0.0f;
  }
  #pragma unroll
  for (int nt = 0; nt < 5; ++nt){
    bool valid = (nt*16 + fm) < ncol;
    #pragma unroll
    for (int r = 0; r < 4; ++r){
      float ev = valid ? __expf((acc[nt][r] - mx[r]) * scale) : 0.0f;
      e[nt][r] = ev; sm[r] += ev;
    }
  }
  #pragma unroll
  for (int r = 0; r < 4; ++r){
    #pragma unroll
    for (int m = 1; m < 16; m <<= 1) sm[r] += __shfl_xor(sm[r], m);
    sm[r] = 1.0f / sm[r];
  }
  #pragma unroll
  for (int nt = 0; nt < 5; ++nt)
    #pragma unroll
    for (int r = 0; r < 4; ++r)
      psf[(fq*4 + r)*105 + nt*16 + fm] = e[nt][r] * sm[r];
  __syncthreads();

  const u16* vbase = qkv + ((size_t)(b*T_ + c0)) * 1536 + 1024 + h*DK_;
  #pragma unroll
  for (int it = 0; it < 20; ++it){
    int i = it*256 + lane*4; int s = i >> 6; int d = i & 63;
    ushort4 w = *(const ushort4*)(vbase + (size_t)s * 1536 + d);
    float4 f; f.x = bf2f(w.x); f.y = bf2f(w.y); f.z = bf2f(w.z); f.w = bf2f(w.w);
    *(float4*)(vf + s*64 + d) = f;
  }
  __syncthreads();

  float oacc[16];
  #pragma unroll
  for (int ii = 0; ii < 16; ++ii) oacc[ii] = 0.0f;
  const float* psr = psf + fm*105;
  const float* vcol = vf + fq*16;
  for (int s = 0; s < 80; ++s){
    float pv = psr[s];
    const float* vr = vcol + s*64;
    float4 v0 = *(const float4*)(vr);
    float4 v1 = *(const float4*)(vr + 4);
    float4 v2 = *(const float4*)(vr + 8);
    float4 v3 = *(const float4*)(vr + 12);
    oacc[0]  += pv*v0.x; oacc[1]  += pv*v0.y; oacc[2]  += pv*v0.z; oacc[3]  += pv*v0.w;
    oacc[4]  += pv*v1.x; oacc[5]  += pv*v1.y; oacc[6]  += pv*v1.z; oacc[7]  += pv*v1.w;
    oacc[8]  += pv*v2.x; oacc[9]  += pv*v2.y; oacc[10] += pv*v2.z; oacc[11] += pv*v2.w;
    oacc[12] += pv*v3.x; oacc[13] += pv*v3.y; oacc[14] += pv*v3.z; oacc[15] += pv*v3.w;
  }
  u16* ob = o + ((size_t)(b*T_ + t0 + fm)) * D_ + h*DK_ + fq*16;
  #pragma unroll
  for (int q4 = 0; q4 < 4; ++q4){
    ushort4 w;
    w.x = f2bf(oacc[q4*4+0]); w.y = f2bf(oacc[q4*4+1]);
    w.z = f2bf(oacc[q4*4+2]); w.w = f2bf(oacc[q4*4+3]);
    *(ushort4*)(ob + q4*4) = w;
  }
}

// ---------------- launcher ---------------------------------------------------
extern "C" void kernel_launch(void* const* d_in, const int* in_sizes, int n_in,
                              void* d_out, int out_size, void* d_ws, size_t ws_size,
                              hipStream_t stream)
{
  int s0 = (n_in >= 24) ? 0 : -1;
  const float* xs   = (const float*)d_in[0];
  const float* pe   = (const float*)d_in[1];
  const float* Wq   = (const float*)d_in[3  + s0];
  const float* bq   = (const float*)d_in[4  + s0];
  const float* Wk   = (const float*)d_in[5  + s0];
  const float* bk   = (const float*)d_in[6  + s0];
  const float* Wv   = (const float*)d_in[7  + s0];
  const float* bv   = (const float*)d_in[8  + s0];
  const float* Wo   = (const float*)d_in[9  + s0];
  const float* bo   = (const float*)d_in[10 + s0];
  const float* Wp   = (const float*)d_in[11 + s0];
  const float* pbu  = (const float*)d_in[12 + s0];
  const float* pbv  = (const float*)d_in[13 + s0];
  const float* ln1s = (const float*)d_in[14 + s0];
  const float* ln1b = (const float*)d_in[15 + s0];
  const float* ln2s = (const float*)d_in[16 + s0];
  const float* ln2b = (const float*)d_in[17 + s0];
  const float* W1   = (const float*)d_in[18 + s0];
  const float* b1   = (const float*)d_in[19 + s0];
  const float* W2   = (const float*)d_in[20 + s0];
  const float* b2   = (const float*)d_in[21 + s0];
  const float* lnfs = (const float*)d_in[22 + s0];
  const float* lnfb = (const float*)d_in[23 + s0];

  float* ws = (float*)d_ws;
  size_t cur = 0;
  float* x      = ws + cur;            cur += (size_t)MT_*D_;
  u16*   qkv_bf = (u16*)(ws + cur);    cur += (size_t)MT_*3*D_/2;
  u16*   h_bf   = (u16*)(ws + cur);    cur += (size_t)MT_*D_/2;
  u16*   ob_bf  = (u16*)(ws + cur);    cur += (size_t)MT_*D_/2;
  u16*   pe_bf  = (u16*)(ws + cur);    cur += (size_t)T_*D_/2;
  u16*   pbuf   = (u16*)(ws + cur);    cur += (size_t)L_*T_*D_/2;
  u16*   qkvt   = (u16*)(ws + cur);    cur += (size_t)L_*3*D_*D_/2;
  u16*   wot    = (u16*)(ws + cur);    cur += (size_t)L_*D_*D_/2;
  u16*   w1t    = (u16*)(ws + cur);    cur += (size_t)L_*D_*FF_/2;
  u16*   w2t    = (u16*)(ws + cur);    cur += (size_t)L_*FF_*D_/2;
  u16*   wpt    = (u16*)(ws + cur);    cur += (size_t)L_*D_*D_/2;
  float* bqkv   = ws + cur;            cur += (size_t)L_*3*D_;

  dim3 tb(32, 8);
  transpose_qkv_kernel<<<dim3(48, 16, L_), tb, 0, stream>>>(Wq, Wk, Wv, qkvt);
  transpose_kernel<<<dim3(16, 16, L_), tb, 0, stream>>>(Wo, wot, D_, D_);
  transpose_kernel<<<dim3(64, 16, L_), tb, 0, stream>>>(W1, w1t, D_, FF_);
  transpose_kernel<<<dim3(16, 64, L_), tb, 0, stream>>>(W2, w2t, FF_, D_);
  transpose_kernel<<<dim3(16, 16, L_), tb, 0, stream>>>(Wp, wpt, D_, D_);
  pack_bias_kernel<<<dim3(L_), dim3(512), 0, stream>>>(bq, bk, bv, bqkv);
  init_kernel<<<dim3(512), dim3(256), 0, stream>>>(xs, pe, x, pe_bf);

  dim3 blk(256);
  // P[l] = pe @ Wp[l]: M=512,N=512,K=512, z indexes layers, bf16 out
  mgemm_kernel<<<dim3(8, 4, L_), blk, 0, stream>>>(
      pe_bf, wpt, nullptr, nullptr, pbuf, T_, D_, D_, 0, 1,
      (size_t)D_*D_, (size_t)T_*D_, 0);

  for (int l = 0; l < L_; ++l){
    ln_kernel<0><<<dim3(MT_/4), blk, 0, stream>>>(x, ln1s + l*D_, ln1b + l*D_, h_bf);
    // QKV: M=4096, N=1536, K=512, grid 24x32 = 768 blocks, bf16 out
    mgemm_kernel<<<dim3(24, 32, 1), blk, 0, stream>>>(
        h_bf, qkvt + (size_t)l*3*D_*D_, bqkv + l*3*D_, nullptr, qkv_bf,
        MT_, 3*D_, D_, 0, 1, 0, 0, 0);
    attn_kernel<<<dim3(T_/CS_, H_, B_), dim3(64), 0, stream>>>(
        qkv_bf, pbuf + (size_t)l*T_*D_, pbu + l*H_*DK_, pbv + l*H_*DK_, ob_bf);
    // O-proj: split-K=2 (kchunk=256), atomic into x (x holds residual)
    mgemm_kernel<<<dim3(8, 32, 2), blk, 0, stream>>>(
        ob_bf, wot + (size_t)l*D_*D_, bo + l*D_, nullptr, x,
        MT_, D_, D_, 0, 0, 0, 0, 256);
    ln_kernel<0><<<dim3(MT_/4), blk, 0, stream>>>(x, ln2s + l*D_, ln2b + l*D_, h_bf);
    // Fused FF: x += relu(h@W1+b1)@W2 + b2, grid 256 (16 rows/block)
    ffused_kernel<<<dim3(MT_/16), blk, 0, stream>>>(
        h_bf, w1t + (size_t)l*D_*FF_, b1 + l*FF_,
        w2t + (size_t)l*FF_*D_, b2 + l*D_, x);
  }
  ln_kernel<1><<<dim3(MT_/4), blk, 0, stream>>>(x, lnfs, lnfb, d_out);
}

// Round 11
// 934.096 us; speedup vs baseline: 2.0576x; 2.0576x over previous
//
#include <hip/hip_runtime.h>

// Problem constants (B,T,D,H,FF,L,CS,LC) = (8,512,512,8,2048,6,16,4)
#define B_ 8
#define T_ 512
#define D_ 512
#define H_ 8
#define FF_ 2048
#define L_ 6
#define CS_ 16
#define LC_ 4
#define DK_ 64
#define MT_ (B_*T_)   // 4096 rows

typedef unsigned short u16;  // raw bf16
typedef __attribute__((ext_vector_type(8))) short bf8_t;   // 8 x bf16 (4 VGPR)
typedef __attribute__((ext_vector_type(4))) float f4_t;    // 4 x f32 acc

__device__ __forceinline__ float bf2f(u16 u){
  union { unsigned int i; float f; } c; c.i = ((unsigned int)u) << 16; return c.f;
}
__device__ __forceinline__ u16 f2bf(float f){
  union { float f; unsigned int i; } c; c.f = f;
  unsigned int x = c.i;
  return (u16)((x + 0x7FFFu + ((x >> 16) & 1u)) >> 16);  // RNE
}
__device__ __forceinline__ void ld_lds16(const u16* gp, u16* lp){
  __builtin_amdgcn_global_load_lds((const __attribute__((address_space(1))) void*)gp,
                                   (__attribute__((address_space(3))) void*)lp, 16, 0, 0);
}

// ---------------- init: x = xs*sqrt(D) (f32), pe_bf = bf16(pos_emb) ----------
__global__ void init_kernel(const float* __restrict__ xs, const float* __restrict__ pe,
                            float* __restrict__ x, u16* __restrict__ pe_bf)
{
  int stride = gridDim.x * blockDim.x;
  int i0 = blockIdx.x * blockDim.x + threadIdx.x;
  const float s = 22.62741699796952f;  // sqrt(512)
  for (int i = i0; i < B_*T_*D_; i += stride) x[i] = xs[i] * s;
  for (int i = i0; i < T_*D_;    i += stride) pe_bf[i] = f2bf(pe[i]);
}

// ---------------- generic transpose+convert: in f32 [K][N] -> out bf16 [N][K]
__global__ void transpose_kernel(const float* __restrict__ in, u16* __restrict__ out,
                                 int K, int N)
{
  __shared__ float tile[32][33];
  int l = blockIdx.z;
  const float* src = in + (size_t)l * K * N;
  u16* dst = out + (size_t)l * N * K;
  int n0 = blockIdx.x * 32, k0 = blockIdx.y * 32;
  int tx = threadIdx.x, ty = threadIdx.y;
  #pragma unroll
  for (int i = 0; i < 4; ++i)
    tile[ty + i*8][tx] = src[(size_t)(k0 + ty + i*8) * N + n0 + tx];
  __syncthreads();
  #pragma unroll
  for (int i = 0; i < 4; ++i)
    dst[(size_t)(n0 + ty + i*8) * K + k0 + tx] = f2bf(tile[tx][ty + i*8]);
}

// ---------------- QKV packed transpose ---------------------------------------
__global__ void transpose_qkv_kernel(const float* __restrict__ Wq, const float* __restrict__ Wk,
                                     const float* __restrict__ Wv, u16* __restrict__ out)
{
  __shared__ float tile[32][33];
  int l = blockIdx.z;
  int n0 = blockIdx.x * 32, k0 = blockIdx.y * 32;
  const float* W = (n0 < 512) ? Wq : (n0 < 1024 ? Wk : Wv);
  int nn0 = n0 & 511;
  const float* src = W + (size_t)l * D_ * D_;
  u16* dst = out + (size_t)l * 3 * D_ * D_;
  int tx = threadIdx.x, ty = threadIdx.y;
  #pragma unroll
  for (int i = 0; i < 4; ++i)
    tile[ty + i*8][tx] = src[(size_t)(k0 + ty + i*8) * D_ + nn0 + tx];
  __syncthreads();
  #pragma unroll
  for (int i = 0; i < 4; ++i)
    dst[(size_t)(n0 + ty + i*8) * D_ + k0 + tx] = f2bf(tile[tx][ty + i*8]);
}

// ---------------- bias pack: bqkv[l][1536] -----------------------------------
__global__ void pack_bias_kernel(const float* __restrict__ bq, const float* __restrict__ bk,
                                 const float* __restrict__ bv, float* __restrict__ out)
{
  int l = blockIdx.x, t = threadIdx.x;  // 512 threads
  out[l*1536 + t]        = bq[l*512 + t];
  out[l*1536 + 512  + t] = bk[l*512 + t];
  out[l*1536 + 1024 + t] = bv[l*512 + t];
}

// ---------------- LayerNorm: one wave per row, 4 rows/block ------------------
template <int OUTMODE>
__global__ __launch_bounds__(256) void ln_kernel(const float* __restrict__ x,
    const float* __restrict__ g, const float* __restrict__ b, void* __restrict__ outp)
{
  int lane = threadIdx.x & 63;
  int row  = (blockIdx.x << 2) + (threadIdx.x >> 6);
  const float* xr = x + (size_t)row * D_;
  int d = lane * 8;
  float4 a0 = *(const float4*)(xr + d);
  float4 a1 = *(const float4*)(xr + d + 4);
  float s  = a0.x+a0.y+a0.z+a0.w + a1.x+a1.y+a1.z+a1.w;
  float s2 = a0.x*a0.x+a0.y*a0.y+a0.z*a0.z+a0.w*a0.w
           + a1.x*a1.x+a1.y*a1.y+a1.z*a1.z+a1.w*a1.w;
  #pragma unroll
  for (int off = 32; off > 0; off >>= 1){ s += __shfl_xor(s, off); s2 += __shfl_xor(s2, off); }
  float m  = s * (1.0f / D_);
  float var = s2 * (1.0f / D_) - m*m;
  float rs = rsqrtf(var + 1e-5f);
  float4 g0 = *(const float4*)(g + d), g1 = *(const float4*)(g + d + 4);
  float4 b0 = *(const float4*)(b + d), b1 = *(const float4*)(b + d + 4);
  float o[8];
  o[0]=(a0.x-m)*rs*g0.x+b0.x; o[1]=(a0.y-m)*rs*g0.y+b0.y;
  o[2]=(a0.z-m)*rs*g0.z+b0.z; o[3]=(a0.w-m)*rs*g0.w+b0.w;
  o[4]=(a1.x-m)*rs*g1.x+b1.x; o[5]=(a1.y-m)*rs*g1.y+b1.y;
  o[6]=(a1.z-m)*rs*g1.z+b1.z; o[7]=(a1.w-m)*rs*g1.w+b1.w;
  if (OUTMODE == 1){
    float* outr = (float*)outp + (size_t)row * D_ + d;
    *(float4*)(outr)     = make_float4(o[0],o[1],o[2],o[3]);
    *(float4*)(outr + 4) = make_float4(o[4],o[5],o[6],o[7]);
  } else {
    u16* outr = (u16*)outp + (size_t)row * D_ + d;
    ushort4 w0, w1;
    w0.x=f2bf(o[0]); w0.y=f2bf(o[1]); w0.z=f2bf(o[2]); w0.w=f2bf(o[3]);
    w1.x=f2bf(o[4]); w1.y=f2bf(o[5]); w1.z=f2bf(o[6]); w1.w=f2bf(o[7]);
    *(ushort4*)(outr)     = w0;
    *(ushort4*)(outr + 4) = w1;
  }
}

// ---------------- MFMA GEMM: 3-deep pipeline, split-K opt, XCD swizzle -------
// C[M][N] = A[M][K](bf16) @ Bt[N][K](bf16)^T
// tile 128(M) x 64(N), BK=32, 256 thr = 4 waves (2x2), wave tile 64x32.
// XCD swizzle: dispatch assigns block i -> XCD i%8; remap (bx,by) so each XCD
// owns a contiguous band of m-blocks across ALL n-blocks -> A-tile n-refetches
// hit that XCD's L2 instead of HBM. Identity when gridDim.y % 8 != 0.
__global__ __launch_bounds__(256) void mgemm_kernel(
    const u16* __restrict__ A, const u16* __restrict__ Bt,
    const float* __restrict__ bias, const float* __restrict__ resid,
    void* __restrict__ C, int M, int N, int K,
    int relu, int bf16out, size_t wstride, size_t cstride, int kchunk)
{
  constexpr int TN = 64, NT = 2, S = 3;
  size_t coff = 0;
  int kbeg = 0, kend = K;
  if (kchunk > 0){
    kbeg = blockIdx.z * kchunk; kend = kbeg + kchunk;
  } else {
    Bt += (size_t)blockIdx.z * wstride;
    coff = (size_t)blockIdx.z * cstride;
  }

  // ---- XCD-aware index remap ----
  int nIdx = blockIdx.x, mIdx = blockIdx.y;
  int nblk = gridDim.x, mblk = gridDim.y;
  if ((mblk & 7) == 0){
    int linear = mIdx * nblk + nIdx;
    int xcd = linear & 7;
    int pos = linear >> 3;
    nIdx = pos % nblk;
    mIdx = (pos / nblk) * 8 + xcd;   // band of mblk/8 m-blocks per XCD
  }

  __shared__ u16 As[3][128 * 32];
  __shared__ u16 Bs[3][TN * 32];

  int tid  = threadIdx.x;
  int wave = tid >> 6, lane = tid & 63;
  int wm = wave >> 1, wn = wave & 1;
  int fm = lane & 15, fq = lane >> 4;

  int m0 = mIdx * 128, n0 = nIdx * TN;

  f4_t acc[4][NT];
  #pragma unroll
  for (int i = 0; i < 4; ++i)
    #pragma unroll
    for (int j = 0; j < NT; ++j) acc[i][j] = (f4_t)0.0f;

  int srow = lane >> 2;
  int selem = (lane & 3) << 3;

  auto stage = [&](int bufi, int k0){
    #pragma unroll
    for (int j = 0; j < 2; ++j){
      int c = wave * 2 + j;
      ld_lds16(A + (size_t)(m0 + c*16 + srow) * K + k0 + selem, &As[bufi][c * 512]);
    }
    ld_lds16(Bt + (size_t)(n0 + wave*16 + srow) * K + k0 + selem, &Bs[bufi][wave * 512]);
  };

  stage(0, kbeg);
  if (kbeg + 32 < kend) stage(1, kbeg + 32);
  int buf = 0;
  for (int k0 = kbeg; k0 < kend; k0 += 32){
    if (k0 + 64 < kend){
      stage((buf + 2) % 3, k0 + 64);
      asm volatile("s_waitcnt vmcnt(%0)" :: "n"(2*S) : "memory");
    } else if (k0 + 32 < kend){
      asm volatile("s_waitcnt vmcnt(%0)" :: "n"(S) : "memory");
    } else {
      asm volatile("s_waitcnt vmcnt(0)" ::: "memory");
    }
    asm volatile("s_barrier" ::: "memory");

    bf8_t af[4], bfr[NT];
    #pragma unroll
    for (int mi = 0; mi < 4; ++mi)
      af[mi] = *(const bf8_t*)&As[buf][(wm*64 + mi*16 + fm) * 32 + fq*8];
    #pragma unroll
    for (int nj = 0; nj < NT; ++nj)
      bfr[nj] = *(const bf8_t*)&Bs[buf][(wn*32 + nj*16 + fm) * 32 + fq*8];
    #pragma unroll
    for (int mi = 0; mi < 4; ++mi)
      #pragma unroll
      for (int nj = 0; nj < NT; ++nj)
        acc[mi][nj] = __builtin_amdgcn_mfma_f32_16x16x32_bf16(af[mi], bfr[nj], acc[mi][nj], 0, 0, 0);

    asm volatile("s_barrier" ::: "memory");
    buf = (buf + 1) % 3;
  }

  int rbase = m0 + wm*64, cbase = n0 + wn*32;
  if (kchunk > 0){
    int addb = (blockIdx.z == 0) && bias;
    #pragma unroll
    for (int mi = 0; mi < 4; ++mi){
      #pragma unroll
      for (int nj = 0; nj < NT; ++nj){
        int col = cbase + nj*16 + fm;
        float bia = addb ? bias[col] : 0.0f;
        #pragma unroll
        for (int r = 0; r < 4; ++r){
          int row = rbase + mi*16 + fq*4 + r;
          atomicAdd((float*)C + (size_t)row * N + col, acc[mi][nj][r] + bia);
        }
      }
    }
  } else {
    #pragma unroll
    for (int mi = 0; mi < 4; ++mi){
      #pragma unroll
      for (int nj = 0; nj < NT; ++nj){
        int col = cbase + nj*16 + fm;
        float bia = bias ? bias[col] : 0.0f;
        #pragma unroll
        for (int r = 0; r < 4; ++r){
          int row = rbase + mi*16 + fq*4 + r;
          size_t idx = coff + (size_t)row * N + col;
          float val = acc[mi][nj][r] + bia;
          if (relu)  val = fmaxf(val, 0.0f);
          if (resid) val += resid[idx];
          if (bf16out) ((u16*)C)[idx] = f2bf(val);
          else         ((float*)C)[idx] = val;
        }
      }
    }
  }
}

// ---------------- Fused chunked attention (single-wave MFMA) ------------------
__global__ __launch_bounds__(64) void attn_kernel(
    const u16* __restrict__ qkv, const u16* __restrict__ p,
    const float* __restrict__ pbu, const float* __restrict__ pbv,
    u16* __restrict__ o)
{
  int ci = blockIdx.x, h = blockIdx.y, b = blockIdx.z;
  int t0 = ci * CS_;
  int cb = ci - LC_; if (cb < 0) cb = 0;
  int c0 = cb * CS_;
  int ncol = (ci + 1) * CS_ - c0;   // 16..80

  __shared__ u16 smem[15648];
  u16* qu = smem;                         // [16][64]
  u16* qv = smem + 1024;                  // [16][64]
  u16* kp = smem + 2048;                  // [80][64] K tile
  u16* pp = smem + 2048 + 5120;           // [80][64] P tile
  float* vf  = (float*)(smem + 2048);     // [80][64] f32 (aliases kp+pp)
  float* psf = (float*)(smem + 12288);    // [16][105] f32

  int lane = threadIdx.x;
  int fm = lane & 15, fq = lane >> 4;

  const u16* kbase = qkv + ((size_t)(b*T_ + c0)) * 1536 + 512 + h*DK_;
  const u16* pbase = p + (size_t)c0 * D_ + h*DK_;
  int srow8 = lane >> 3, scol = (lane & 7) << 3;
  #pragma unroll
  for (int c = 0; c < 10; ++c){
    ld_lds16(kbase + (size_t)(c*8 + srow8) * 1536 + scol, kp + c*512);
    ld_lds16(pbase + (size_t)(c*8 + srow8) * D_   + scol, pp + c*512);
  }
  const u16* qbase = qkv + ((size_t)(b*T_ + t0)) * 1536 + h*DK_;
  #pragma unroll
  for (int it = 0; it < 4; ++it){
    int i = it*256 + lane*4; int r = i >> 6; int d = i & 63;
    ushort4 w = *(const ushort4*)(qbase + (size_t)r * 1536 + d);
    float4 bu = *(const float4*)(pbu + h*DK_ + d);
    float4 bv = *(const float4*)(pbv + h*DK_ + d);
    ushort4 ou, ov;
    ou.x = f2bf(bf2f(w.x) + bu.x); ou.y = f2bf(bf2f(w.y) + bu.y);
    ou.z = f2bf(bf2f(w.z) + bu.z); ou.w = f2bf(bf2f(w.w) + bu.w);
    ov.x = f2bf(bf2f(w.x) + bv.x); ov.y = f2bf(bf2f(w.y) + bv.y);
    ov.z = f2bf(bf2f(w.z) + bv.z); ov.w = f2bf(bf2f(w.w) + bv.w);
    *(ushort4*)(qu + r*64 + d) = ou;
    *(ushort4*)(qv + r*64 + d) = ov;
  }
  __syncthreads();

  bf8_t au0 = *(const bf8_t*)(qu + fm*64 + fq*8);
  bf8_t au1 = *(const bf8_t*)(qu + fm*64 + 32 + fq*8);
  bf8_t av0 = *(const bf8_t*)(qv + fm*64 + fq*8);
  bf8_t av1 = *(const bf8_t*)(qv + fm*64 + 32 + fq*8);
  f4_t acc[5];
  #pragma unroll
  for (int nt = 0; nt < 5; ++nt) acc[nt] = (f4_t)0.0f;
  #pragma unroll
  for (int nt = 0; nt < 5; ++nt){
    const u16* kr = kp + (nt*16 + fm)*64;
    const u16* pr = pp + (nt*16 + fm)*64;
    bf8_t bk0 = *(const bf8_t*)(kr + fq*8);
    bf8_t bk1 = *(const bf8_t*)(kr + 32 + fq*8);
    bf8_t bp0 = *(const bf8_t*)(pr + fq*8);
    bf8_t bp1 = *(const bf8_t*)(pr + 32 + fq*8);
    f4_t a = acc[nt];
    a = __builtin_amdgcn_mfma_f32_16x16x32_bf16(au0, bk0, a, 0, 0, 0);
    a = __builtin_amdgcn_mfma_f32_16x16x32_bf16(au1, bk1, a, 0, 0, 0);
    a = __builtin_amdgcn_mfma_f32_16x16x32_bf16(av0, bp0, a, 0, 0, 0);
    a = __builtin_amdgcn_mfma_f32_16x16x32_bf16(av1, bp1, a, 0, 0, 0);
    acc[nt] = a;
  }

  const float scale = 0.125f;
  float mx[4], sm[4];
  float e[5][4];
  #pragma unroll
  for (int r = 0; r < 4; ++r) mx[r] = -3.0e38f;
  #pragma unroll
  for (int nt = 0; nt < 5; ++nt){
    bool valid = (nt*16 + fm) < ncol;
    #pragma unroll
    for (int r = 0; r < 4; ++r){
      float v = valid ? acc[nt][r] : -3.0e38f;
      mx[r] = fmaxf(mx[r], v);
    }
  }
  #pragma unroll
  for (int r = 0; r < 4; ++r){
    #pragma unroll
    for (int m = 1; m < 16; m <<= 1) mx[r] = fmaxf(mx[r], __shfl_xor(mx[r], m));
    sm[r] = 0.0f;
  }
  #pragma unroll
  for (int nt = 0; nt < 5; ++nt){
    bool valid = (nt*16 + fm) < ncol;
    #pragma unroll
    for (int r = 0; r < 4; ++r){
      float ev = valid ? __expf((acc[nt][r] - mx[r]) * scale) : 0.0f;
      e[nt][r] = ev; sm[r] += ev;
    }
  }
  #pragma unroll
  for (int r = 0; r < 4; ++r){
    #pragma unroll
    for (int m = 1; m < 16; m <<= 1) sm[r] += __shfl_xor(sm[r], m);
    sm[r] = 1.0f / sm[r];
  }
  #pragma unroll
  for (int nt = 0; nt < 5; ++nt)
    #pragma unroll
    for (int r = 0; r < 4; ++r)
      psf[(fq*4 + r)*105 + nt*16 + fm] = e[nt][r] * sm[r];
  __syncthreads();

  const u16* vbase = qkv + ((size_t)(b*T_ + c0)) * 1536 + 1024 + h*DK_;
  #pragma unroll
  for (int it = 0; it < 20; ++it){
    int i = it*256 + lane*4; int s = i >> 6; int d = i & 63;
    ushort4 w = *(const ushort4*)(vbase + (size_t)s * 1536 + d);
    float4 f; f.x = bf2f(w.x); f.y = bf2f(w.y); f.z = bf2f(w.z); f.w = bf2f(w.w);
    *(float4*)(vf + s*64 + d) = f;
  }
  __syncthreads();

  float oacc[16];
  #pragma unroll
  for (int ii = 0; ii < 16; ++ii) oacc[ii] = 0.0f;
  const float* psr = psf + fm*105;
  const float* vcol = vf + fq*16;
  for (int s = 0; s < 80; ++s){
    float pv = psr[s];
    const float* vr = vcol + s*64;
    float4 v0 = *(const float4*)(vr);
    float4 v1 = *(const float4*)(vr + 4);
    float4 v2 = *(const float4*)(vr + 8);
    float4 v3 = *(const float4*)(vr + 12);
    oacc[0]  += pv*v0.x; oacc[1]  += pv*v0.y; oacc[2]  += pv*v0.z; oacc[3]  += pv*v0.w;
    oacc[4]  += pv*v1.x; oacc[5]  += pv*v1.y; oacc[6]  += pv*v1.z; oacc[7]  += pv*v1.w;
    oacc[8]  += pv*v2.x; oacc[9]  += pv*v2.y; oacc[10] += pv*v2.z; oacc[11] += pv*v2.w;
    oacc[12] += pv*v3.x; oacc[13] += pv*v3.y; oacc[14] += pv*v3.z; oacc[15] += pv*v3.w;
  }
  u16* ob = o + ((size_t)(b*T_ + t0 + fm)) * D_ + h*DK_ + fq*16;
  #pragma unroll
  for (int q4 = 0; q4 < 4; ++q4){
    ushort4 w;
    w.x = f2bf(oacc[q4*4+0]); w.y = f2bf(oacc[q4*4+1]);
    w.z = f2bf(oacc[q4*4+2]); w.w = f2bf(oacc[q4*4+3]);
    *(ushort4*)(ob + q4*4) = w;
  }
}

// ---------------- launcher ---------------------------------------------------
extern "C" void kernel_launch(void* const* d_in, const int* in_sizes, int n_in,
                              void* d_out, int out_size, void* d_ws, size_t ws_size,
                              hipStream_t stream)
{
  int s0 = (n_in >= 24) ? 0 : -1;
  const float* xs   = (const float*)d_in[0];
  const float* pe   = (const float*)d_in[1];
  const float* Wq   = (const float*)d_in[3  + s0];
  const float* bq   = (const float*)d_in[4  + s0];
  const float* Wk   = (const float*)d_in[5  + s0];
  const float* bk   = (const float*)d_in[6  + s0];
  const float* Wv   = (const float*)d_in[7  + s0];
  const float* bv   = (const float*)d_in[8  + s0];
  const float* Wo   = (const float*)d_in[9  + s0];
  const float* bo   = (const float*)d_in[10 + s0];
  const float* Wp   = (const float*)d_in[11 + s0];
  const float* pbu  = (const float*)d_in[12 + s0];
  const float* pbv  = (const float*)d_in[13 + s0];
  const float* ln1s = (const float*)d_in[14 + s0];
  const float* ln1b = (const float*)d_in[15 + s0];
  const float* ln2s = (const float*)d_in[16 + s0];
  const float* ln2b = (const float*)d_in[17 + s0];
  const float* W1   = (const float*)d_in[18 + s0];
  const float* b1   = (const float*)d_in[19 + s0];
  const float* W2   = (const float*)d_in[20 + s0];
  const float* b2   = (const float*)d_in[21 + s0];
  const float* lnfs = (const float*)d_in[22 + s0];
  const float* lnfb = (const float*)d_in[23 + s0];

  float* ws = (float*)d_ws;
  size_t cur = 0;
  float* x      = ws + cur;            cur += (size_t)MT_*D_;
  u16*   region = (u16*)(ws + cur);    cur += (size_t)MT_*FF_/2;
  u16*   qkv_bf = region;
  u16*   ff_bf  = region;
  u16*   h_bf   = (u16*)(ws + cur);    cur += (size_t)MT_*D_/2;
  u16*   ob_bf  = (u16*)(ws + cur);    cur += (size_t)MT_*D_/2;
  u16*   pe_bf  = (u16*)(ws + cur);    cur += (size_t)T_*D_/2;
  u16*   pbuf   = (u16*)(ws + cur);    cur += (size_t)L_*T_*D_/2;
  u16*   qkvt   = (u16*)(ws + cur);    cur += (size_t)L_*3*D_*D_/2;
  u16*   wot    = (u16*)(ws + cur);    cur += (size_t)L_*D_*D_/2;
  u16*   w1t    = (u16*)(ws + cur);    cur += (size_t)L_*D_*FF_/2;
  u16*   w2t    = (u16*)(ws + cur);    cur += (size_t)L_*FF_*D_/2;
  u16*   wpt    = (u16*)(ws + cur);    cur += (size_t)L_*D_*D_/2;
  float* bqkv   = ws + cur;            cur += (size_t)L_*3*D_;

  dim3 tb(32, 8);
  transpose_qkv_kernel<<<dim3(48, 16, L_), tb, 0, stream>>>(Wq, Wk, Wv, qkvt);
  transpose_kernel<<<dim3(16, 16, L_), tb, 0, stream>>>(Wo, wot, D_, D_);
  transpose_kernel<<<dim3(64, 16, L_), tb, 0, stream>>>(W1, w1t, D_, FF_);
  transpose_kernel<<<dim3(16, 64, L_), tb, 0, stream>>>(W2, w2t, FF_, D_);
  transpose_kernel<<<dim3(16, 16, L_), tb, 0, stream>>>(Wp, wpt, D_, D_);
  pack_bias_kernel<<<dim3(L_), dim3(512), 0, stream>>>(bq, bk, bv, bqkv);
  init_kernel<<<dim3(512), dim3(256), 0, stream>>>(xs, pe, x, pe_bf);

  dim3 blk(256);
  // P[l] = pe @ Wp[l]: M=512,N=512,K=512, z indexes layers, bf16 out
  mgemm_kernel<<<dim3(8, 4, L_), blk, 0, stream>>>(
      pe_bf, wpt, nullptr, nullptr, pbuf, T_, D_, D_, 0, 1,
      (size_t)D_*D_, (size_t)T_*D_, 0);

  for (int l = 0; l < L_; ++l){
    ln_kernel<0><<<dim3(MT_/4), blk, 0, stream>>>(x, ln1s + l*D_, ln1b + l*D_, h_bf);
    // QKV: M=4096, N=1536, K=512, grid 24x32 = 768 blocks, bf16 out
    mgemm_kernel<<<dim3(24, 32, 1), blk, 0, stream>>>(
        h_bf, qkvt + (size_t)l*3*D_*D_, bqkv + l*3*D_, nullptr, qkv_bf,
        MT_, 3*D_, D_, 0, 1, 0, 0, 0);
    attn_kernel<<<dim3(T_/CS_, H_, B_), dim3(64), 0, stream>>>(
        qkv_bf, pbuf + (size_t)l*T_*D_, pbu + l*H_*DK_, pbv + l*H_*DK_, ob_bf);
    // O-proj: split-K=2 (kchunk=256), atomic into x (x holds residual)
    mgemm_kernel<<<dim3(8, 32, 2), blk, 0, stream>>>(
        ob_bf, wot + (size_t)l*D_*D_, bo + l*D_, nullptr, x,
        MT_, D_, D_, 0, 0, 0, 0, 256);
    ln_kernel<0><<<dim3(MT_/4), blk, 0, stream>>>(x, ln2s + l*D_, ln2b + l*D_, h_bf);
    // FF1: M=4096, N=2048, K=512, grid 32x32 = 1024 blocks, relu, bf16 out
    mgemm_kernel<<<dim3(32, 32, 1), blk, 0, stream>>>(
        h_bf, w1t + (size_t)l*D_*FF_, b1 + l*FF_, nullptr, ff_bf,
        MT_, FF_, D_, 1, 1, 0, 0, 0);
    // FF2: split-K=4 (kchunk=512), atomic into x
    mgemm_kernel<<<dim3(8, 32, 4), blk, 0, stream>>>(
        ff_bf, w2t + (size_t)l*FF_*D_, b2 + l*D_, nullptr, x,
        MT_, D_, FF_, 0, 0, 0, 0, 512);
  }
  ln_kernel<1><<<dim3(MT_/4), blk, 0, stream>>>(x, lnfs, lnfb, d_out);
}